// Round 1
// baseline (1696.478 us; speedup 1.0000x reference)
//
#include <hip/hip_runtime.h>
#include <hip/hip_bf16.h>
#include <stdint.h>

#define NN   100000
#define NE   1600000
#define FIN  128
#define FOUT 200
#define FPAD 208   // 13 * 16

typedef __attribute__((ext_vector_type(8))) short short8;
typedef __attribute__((ext_vector_type(4))) float f32x4;

__device__ __forceinline__ short f2bf(float f) {
    __hip_bfloat16 h = __float2bfloat16(f);
    return *reinterpret_cast<short*>(&h);
}

// --- dtype detection: read edge_index as int64; if any value out of [0,NN), it is int32 ---
__global__ void detect_kernel(const long long* ei64, int* flag) {
    int t = blockIdx.x * blockDim.x + threadIdx.x;   // 4096 samples
    long long v = ei64[t];
    if (v < 0 || v >= NN) atomicOr(flag, 1);
}

__global__ void normalize_idx(const void* eiraw, const int* flag, int* rc) {
    int i = blockIdx.x * blockDim.x + threadIdx.x;   // 2*NE exact
    if (*flag) rc[i] = ((const int*)eiraw)[i];
    else       rc[i] = (int)((const long long*)eiraw)[i];
}

__global__ void deg_kernel(const int* rc, const float* w, float* deg) {
    int e = blockIdx.x * blockDim.x + threadIdx.x;   // NE exact
    atomicAdd(&deg[rc[e]], w[e]);
}

__global__ void norm_kernel(const int* rc, const float* w, const float* deg, float* nrm) {
    int e = blockIdx.x * blockDim.x + threadIdx.x;   // NE exact
    int r = rc[e], c = rc[NE + e];
    float dr = deg[r], dc = deg[c];
    float ir = dr > 0.f ? rsqrtf(dr) : 0.f;
    float ic = dc > 0.f ? rsqrtf(dc) : 0.f;
    nrm[e] = -w[e] * ir * ic;
}

// dst[row] += nrm * src[col]   one thread per (edge, feature)
__global__ void scatter_kernel(const int* __restrict__ rc, const float* __restrict__ nrm,
                               const float* __restrict__ src, float* __restrict__ dst) {
    long long gid = (long long)blockIdx.x * blockDim.x + threadIdx.x;  // NE*128 exact
    int e = (int)(gid >> 7);
    int f = (int)(gid & 127);
    int r = rc[e], c = rc[NE + e];
    float v = nrm[e] * src[(long long)c * FIN + f];
    atomicAdd(&dst[(long long)r * FIN + f], v);
}

__global__ void fixup_kernel(const float* __restrict__ x, float* __restrict__ S) {
    int i = blockIdx.x * blockDim.x + threadIdx.x;   // NN*FIN exact
    S[i] = 2.f * S[i] - x[i];
}

// Pack W into bf16, transposed to [col][k], zero-padded to FPAD cols.
// Layout: s0 [208][128] at 0, s1 [208][256] at 208*128, s2 [208][384] at 208*384.
__global__ void wprep_kernel(const float* __restrict__ W1, const float* __restrict__ W2,
                             const float* __restrict__ W3, __hip_bfloat16* __restrict__ Wt) {
    int gid = blockIdx.x * blockDim.x + threadIdx.x;   // FPAD*768 exact
    int off, K; const float* W;
    if (gid < FPAD * 128)      { K = 128; W = W1; off = gid; }
    else if (gid < FPAD * 384) { K = 256; W = W2; off = gid - FPAD * 128; }
    else                       { K = 384; W = W3; off = gid - FPAD * 384; }
    int col = off / K, k = off % K;
    float v = (col < FOUT) ? W[k * FOUT + col] : 0.f;   // W flat is [K][FOUT]
    Wt[gid] = __float2bfloat16(v);
}

// out_s[n, :] = sum_{k-panels} A_k[n] @ W_{s,k} + b_s ; BM=64, BN=208, 4 waves.
__launch_bounds__(256)
__global__ void gemm_kernel(const float* __restrict__ x, const float* __restrict__ t1,
                            const float* __restrict__ t2, const __hip_bfloat16* __restrict__ Wt,
                            const float* __restrict__ b1, const float* __restrict__ b2,
                            const float* __restrict__ b3, float* __restrict__ out) {
    __shared__ __align__(16) __hip_bfloat16 As[64][40];
    __shared__ __align__(16) __hip_bfloat16 Bs[FPAD][40];

    const int s  = blockIdx.y;
    const int n0 = blockIdx.x * 64;
    const int Ks = 128 * (s + 1);
    const __hip_bfloat16* Wts = Wt + (s == 0 ? 0 : (s == 1 ? FPAD * 128 : FPAD * 384));

    const int tid  = threadIdx.x;
    const int wave = tid >> 6;
    const int lane = tid & 63;
    const int l15  = lane & 15;
    const int lhi  = lane >> 4;

    f32x4 acc[13];
    #pragma unroll
    for (int t = 0; t < 13; ++t) acc[t] = {0.f, 0.f, 0.f, 0.f};

    const int ar   = tid >> 2;         // 0..63 row within tile
    const int ac   = (tid & 3) * 8;    // k offset within 32-chunk
    const int arow = n0 + ar;

    for (int k0 = 0; k0 < Ks; k0 += 32) {
        const float* src = (k0 < 128) ? x : ((k0 < 256) ? t1 : t2);
        const int kk = k0 & 127;
        f32x4 v0 = {0.f,0.f,0.f,0.f}, v1 = {0.f,0.f,0.f,0.f};
        if (arow < NN) {
            const float* p = src + (long long)arow * FIN + kk + ac;
            v0 = *(const f32x4*)p;
            v1 = *(const f32x4*)(p + 4);
        }
        uint4 w0, w1, w2, w3;
        if (tid < FPAD) {
            const uint4* bp = (const uint4*)(Wts + (long long)tid * Ks + k0);
            w0 = bp[0]; w1 = bp[1]; w2 = bp[2]; w3 = bp[3];
        }
        __syncthreads();   // previous iteration's reads done
        short8 ap;
        ap[0] = f2bf(v0[0]); ap[1] = f2bf(v0[1]); ap[2] = f2bf(v0[2]); ap[3] = f2bf(v0[3]);
        ap[4] = f2bf(v1[0]); ap[5] = f2bf(v1[1]); ap[6] = f2bf(v1[2]); ap[7] = f2bf(v1[3]);
        *(short8*)&As[ar][ac] = ap;
        if (tid < FPAD) {
            uint4* bq = (uint4*)&Bs[tid][0];
            bq[0] = w0; bq[1] = w1; bq[2] = w2; bq[3] = w3;
        }
        __syncthreads();
        short8 a = *(const short8*)&As[wave * 16 + l15][lhi * 8];
        #pragma unroll
        for (int t = 0; t < 13; ++t) {
            short8 b = *(const short8*)&Bs[t * 16 + l15][lhi * 8];
            acc[t] = __builtin_amdgcn_mfma_f32_16x16x32_bf16(a, b, acc[t], 0, 0, 0);
        }
    }

    const float* bias = (s == 0) ? b1 : ((s == 1) ? b2 : b3);
    float* outp = out + (long long)s * NN * FOUT;
    const int rbase = n0 + wave * 16 + lhi * 4;
    #pragma unroll
    for (int t = 0; t < 13; ++t) {
        int col = t * 16 + l15;
        if (col < FOUT) {
            float bv = bias[col];
            #pragma unroll
            for (int j = 0; j < 4; ++j) {
                int r = rbase + j;
                if (r < NN) outp[(long long)r * FOUT + col] = acc[t][j] + bv;
            }
        }
    }
}

extern "C" void kernel_launch(void* const* d_in, const int* in_sizes, int n_in,
                              void* d_out, int out_size, void* d_ws, size_t ws_size,
                              hipStream_t stream) {
    const float* x  = (const float*)d_in[0];
    const void*  ei = d_in[1];
    const float* ew = (const float*)d_in[2];
    const float* W1 = (const float*)d_in[3];
    const float* b1 = (const float*)d_in[4];
    const float* W2 = (const float*)d_in[5];
    const float* b2 = (const float*)d_in[6];
    const float* W3 = (const float*)d_in[7];
    const float* b3 = (const float*)d_in[8];
    float* out = (float*)d_out;

    char* ws = (char*)d_ws;
    // layout (bytes):
    // [0,16)            flag
    // [16, 400128)      deg   (N f32)
    // [400128, 51600128)   T1 (N*128 f32)
    // [51600128, 102800128) S (N*128 f32)  -> after fixup holds T2
    // [102800128, 109200128) nrm (E f32)
    // [109200128, 122000128) rc  (2E i32)
    // [122000128, ...)  Wt (bf16, 208*768)
    int*   flag = (int*)(ws + 0);
    float* deg  = (float*)(ws + 16);
    float* T1   = (float*)(ws + 400128);
    float* S    = (float*)(ws + 51600128);
    float* nrm  = (float*)(ws + 102800128);
    int*   rc   = (int*)(ws + 109200128);
    __hip_bfloat16* Wt = (__hip_bfloat16*)(ws + 122000128);

    hipMemsetAsync(d_ws, 0, 102800128, stream);  // flag + deg + T1 + S

    detect_kernel<<<16, 256, 0, stream>>>((const long long*)ei, flag);
    normalize_idx<<<(2 * NE) / 256, 256, 0, stream>>>(ei, flag, rc);
    deg_kernel<<<NE / 256, 256, 0, stream>>>(rc, ew, deg);
    norm_kernel<<<NE / 256, 256, 0, stream>>>(rc, ew, deg, nrm);
    scatter_kernel<<<800000, 256, 0, stream>>>(rc, nrm, x, T1);   // T1 = P(x)
    scatter_kernel<<<800000, 256, 0, stream>>>(rc, nrm, T1, S);   // S = P(T1)
    fixup_kernel<<<(NN * FIN) / 256, 256, 0, stream>>>(x, S);     // S = 2S - x = T2
    wprep_kernel<<<(FPAD * 768) / 256, 256, 0, stream>>>(W1, W2, W3, Wt);
    gemm_kernel<<<dim3((NN + 63) / 64, 3), 256, 0, stream>>>(x, T1, S, Wt, b1, b2, b3, out);
}

// Round 2
// 716.847 us; speedup vs baseline: 2.3666x; 2.3666x over previous
//
#include <hip/hip_runtime.h>
#include <hip/hip_bf16.h>
#include <stdint.h>

#define NN   100000
#define NE   1600000
#define FIN  128
#define FOUT 200
#define FPAD 208   // 13 * 16
#define NBLK 391   // ceil(NN/256)

typedef __attribute__((ext_vector_type(8))) short short8;
typedef __attribute__((ext_vector_type(4))) float f32x4;

__device__ __forceinline__ short f2bf(float f) {
    __hip_bfloat16 h = __float2bfloat16(f);
    return *reinterpret_cast<short*>(&h);
}

__device__ __forceinline__ int getidx(const void* ei, int isI32, long long i) {
    return isI32 ? ((const int*)ei)[i] : (int)((const long long*)ei)[i];
}

// --- dtype detection: read edge_index as int64; if any value out of [0,NN), it is int32 ---
__global__ void detect_kernel(const long long* ei64, int* flag) {
    int t = blockIdx.x * blockDim.x + threadIdx.x;   // 4096 samples
    long long v = ei64[t];
    if (v < 0 || v >= NN) atomicOr(flag, 1);
}

// deg[r] += w ; cnt[r] += 1   (fused)
__global__ void deg_count_kernel(const void* ei, const int* flag, const float* w,
                                 float* deg, int* cnt) {
    int e = blockIdx.x * blockDim.x + threadIdx.x;   // NE exact
    int r = getidx(ei, *flag, e);
    atomicAdd(&deg[r], w[e]);
    atomicAdd(&cnt[r], 1);
}

// hierarchical exclusive scan of cnt -> rowstart
__global__ void scan_block(const int* __restrict__ cnt, int* __restrict__ rowstart,
                           int* __restrict__ bsum) {
    __shared__ int tmp[256];
    int i = blockIdx.x * 256 + threadIdx.x;
    int v = (i < NN) ? cnt[i] : 0;
    tmp[threadIdx.x] = v;
    __syncthreads();
    for (int off = 1; off < 256; off <<= 1) {
        int t = (threadIdx.x >= off) ? tmp[threadIdx.x - off] : 0;
        __syncthreads();
        tmp[threadIdx.x] += t;
        __syncthreads();
    }
    if (i < NN) rowstart[i] = tmp[threadIdx.x] - v;   // block-local exclusive
    if (threadIdx.x == 255) bsum[blockIdx.x] = tmp[255];
}

__global__ void scan_bsums(int* bsum) {   // 1 block, 512 threads
    __shared__ int tmp[512];
    int t = threadIdx.x;
    int v = (t < NBLK) ? bsum[t] : 0;
    tmp[t] = v;
    __syncthreads();
    for (int off = 1; off < 512; off <<= 1) {
        int u = (t >= off) ? tmp[t - off] : 0;
        __syncthreads();
        tmp[t] += u;
        __syncthreads();
    }
    if (t < NBLK) bsum[t] = tmp[t] - v;   // exclusive
}

__global__ void scan_add(int* __restrict__ rowstart, const int* __restrict__ bsum,
                         int* __restrict__ cnt) {
    int i = blockIdx.x * 256 + threadIdx.x;   // covers NN+1
    if (i < NN) {
        rowstart[i] += bsum[i >> 8];
        cnt[i] = 0;                 // reuse cnt as fill counter
    } else if (i == NN) {
        rowstart[NN] = NE;
    }
}

// counting-sort edges by destination row; compute norm inline
__global__ void fill_csr(const void* ei, const int* flag, const float* __restrict__ w,
                         const float* __restrict__ deg, const int* __restrict__ rowstart,
                         int* __restrict__ fill, int* __restrict__ ecol,
                         float* __restrict__ enorm) {
    int e = blockIdx.x * blockDim.x + threadIdx.x;   // NE exact
    int isI32 = *flag;
    int r = getidx(ei, isI32, e);
    int c = getidx(ei, isI32, (long long)NE + e);
    float dr = deg[r], dc = deg[c];
    float ir = dr > 0.f ? rsqrtf(dr) : 0.f;
    float ic = dc > 0.f ? rsqrtf(dc) : 0.f;
    int pos = rowstart[r] + atomicAdd(&fill[r], 1);
    ecol[pos] = c;
    enorm[pos] = -w[e] * ir * ic;
}

// one wave per destination row; MODE 0: dst = P(src); MODE 1: dst = 2*P(src) - x
template <int MODE>
__launch_bounds__(256)
__global__ void gather_prop(const int* __restrict__ rowstart, const int* __restrict__ ecol,
                            const float* __restrict__ enorm, const float* __restrict__ src,
                            const float* __restrict__ x, float* __restrict__ dst) {
    int gw   = (blockIdx.x << 2) + (threadIdx.x >> 6);   // global wave = row
    int lane = threadIdx.x & 63;
    int s = rowstart[gw], eend = rowstart[gw + 1];
    const float2* srcp = (const float2*)src;
    float ax = 0.f, ay = 0.f;
    int e = s;
    for (; e + 1 < eend; e += 2) {
        int c0 = ecol[e];     float w0 = enorm[e];
        int c1 = ecol[e + 1]; float w1 = enorm[e + 1];
        float2 v0 = srcp[(c0 << 6) + lane];
        float2 v1 = srcp[(c1 << 6) + lane];
        ax += w0 * v0.x; ay += w0 * v0.y;
        ax += w1 * v1.x; ay += w1 * v1.y;
    }
    if (e < eend) {
        int c0 = ecol[e]; float w0 = enorm[e];
        float2 v0 = srcp[(c0 << 6) + lane];
        ax += w0 * v0.x; ay += w0 * v0.y;
    }
    float2 o;
    if (MODE == 1) {
        float2 xv = ((const float2*)x)[(gw << 6) + lane];
        o.x = 2.f * ax - xv.x;
        o.y = 2.f * ay - xv.y;
    } else {
        o.x = ax; o.y = ay;
    }
    ((float2*)dst)[(gw << 6) + lane] = o;
}

// Pack W into bf16, transposed to [col][k], zero-padded to FPAD cols.
__global__ void wprep_kernel(const float* __restrict__ W1, const float* __restrict__ W2,
                             const float* __restrict__ W3, __hip_bfloat16* __restrict__ Wt) {
    int gid = blockIdx.x * blockDim.x + threadIdx.x;   // FPAD*768 exact
    int off, K; const float* W;
    if (gid < FPAD * 128)      { K = 128; W = W1; off = gid; }
    else if (gid < FPAD * 384) { K = 256; W = W2; off = gid - FPAD * 128; }
    else                       { K = 384; W = W3; off = gid - FPAD * 384; }
    int col = off / K, k = off % K;
    float v = (col < FOUT) ? W[k * FOUT + col] : 0.f;   // W flat is [K][FOUT]
    Wt[gid] = __float2bfloat16(v);
}

// out_s[n, :] = sum_{k-panels} A_k[n] @ W_{s,k} + b_s ; BM=64, BN=208, 4 waves.
__launch_bounds__(256)
__global__ void gemm_kernel(const float* __restrict__ x, const float* __restrict__ t1,
                            const float* __restrict__ t2, const __hip_bfloat16* __restrict__ Wt,
                            const float* __restrict__ b1, const float* __restrict__ b2,
                            const float* __restrict__ b3, float* __restrict__ out) {
    __shared__ __align__(16) __hip_bfloat16 As[64][40];
    __shared__ __align__(16) __hip_bfloat16 Bs[FPAD][40];

    const int s  = blockIdx.y;
    const int n0 = blockIdx.x * 64;
    const int Ks = 128 * (s + 1);
    const __hip_bfloat16* Wts = Wt + (s == 0 ? 0 : (s == 1 ? FPAD * 128 : FPAD * 384));

    const int tid  = threadIdx.x;
    const int wave = tid >> 6;
    const int lane = tid & 63;
    const int l15  = lane & 15;
    const int lhi  = lane >> 4;

    f32x4 acc[13];
    #pragma unroll
    for (int t = 0; t < 13; ++t) acc[t] = {0.f, 0.f, 0.f, 0.f};

    const int ar   = tid >> 2;
    const int ac   = (tid & 3) * 8;
    const int arow = n0 + ar;

    for (int k0 = 0; k0 < Ks; k0 += 32) {
        const float* src = (k0 < 128) ? x : ((k0 < 256) ? t1 : t2);
        const int kk = k0 & 127;
        f32x4 v0 = {0.f,0.f,0.f,0.f}, v1 = {0.f,0.f,0.f,0.f};
        if (arow < NN) {
            const float* p = src + (long long)arow * FIN + kk + ac;
            v0 = *(const f32x4*)p;
            v1 = *(const f32x4*)(p + 4);
        }
        uint4 w0, w1, w2, w3;
        if (tid < FPAD) {
            const uint4* bp = (const uint4*)(Wts + (long long)tid * Ks + k0);
            w0 = bp[0]; w1 = bp[1]; w2 = bp[2]; w3 = bp[3];
        }
        __syncthreads();
        short8 ap;
        ap[0] = f2bf(v0[0]); ap[1] = f2bf(v0[1]); ap[2] = f2bf(v0[2]); ap[3] = f2bf(v0[3]);
        ap[4] = f2bf(v1[0]); ap[5] = f2bf(v1[1]); ap[6] = f2bf(v1[2]); ap[7] = f2bf(v1[3]);
        *(short8*)&As[ar][ac] = ap;
        if (tid < FPAD) {
            uint4* bq = (uint4*)&Bs[tid][0];
            bq[0] = w0; bq[1] = w1; bq[2] = w2; bq[3] = w3;
        }
        __syncthreads();
        short8 a = *(const short8*)&As[wave * 16 + l15][lhi * 8];
        #pragma unroll
        for (int t = 0; t < 13; ++t) {
            short8 b = *(const short8*)&Bs[t * 16 + l15][lhi * 8];
            acc[t] = __builtin_amdgcn_mfma_f32_16x16x32_bf16(a, b, acc[t], 0, 0, 0);
        }
    }

    const float* bias = (s == 0) ? b1 : ((s == 1) ? b2 : b3);
    float* outp = out + (long long)s * NN * FOUT;
    const int rbase = n0 + wave * 16 + lhi * 4;
    #pragma unroll
    for (int t = 0; t < 13; ++t) {
        int col = t * 16 + l15;
        if (col < FOUT) {
            float bv = bias[col];
            #pragma unroll
            for (int j = 0; j < 4; ++j) {
                int r = rbase + j;
                if (r < NN) outp[(long long)r * FOUT + col] = acc[t][j] + bv;
            }
        }
    }
}

extern "C" void kernel_launch(void* const* d_in, const int* in_sizes, int n_in,
                              void* d_out, int out_size, void* d_ws, size_t ws_size,
                              hipStream_t stream) {
    const float* x  = (const float*)d_in[0];
    const void*  ei = d_in[1];
    const float* ew = (const float*)d_in[2];
    const float* W1 = (const float*)d_in[3];
    const float* b1 = (const float*)d_in[4];
    const float* W2 = (const float*)d_in[5];
    const float* b2 = (const float*)d_in[6];
    const float* W3 = (const float*)d_in[7];
    const float* b3 = (const float*)d_in[8];
    float* out = (float*)d_out;

    char* ws = (char*)d_ws;
    // layout (bytes):
    // [0,16)                flag
    // [16, 400016)          deg      (N f32)         } zeroed
    // [400016, 800016)      cnt/fill (N i32)         } zeroed
    // [800016, 1200020)     rowstart (N+1 i32)
    // [1200032, 1202080)    bsum     (512 i32)
    // [1202080, 7602080)    ecol     (E i32)
    // [7602080, 14002080)   enorm    (E f32)
    // [14002080, 65202080)  T1       (N*128 f32)
    // [65202080, 116402080) T2       (N*128 f32)
    // [116402080, ...)      Wt       (bf16, 208*768)
    int*   flag     = (int*)(ws + 0);
    float* deg      = (float*)(ws + 16);
    int*   cnt      = (int*)(ws + 400016);
    int*   rowstart = (int*)(ws + 800016);
    int*   bsum     = (int*)(ws + 1200032);
    int*   ecol     = (int*)(ws + 1202080);
    float* enorm    = (float*)(ws + 7602080);
    float* T1       = (float*)(ws + 14002080);
    float* T2       = (float*)(ws + 65202080);
    __hip_bfloat16* Wt = (__hip_bfloat16*)(ws + 116402080);

    hipMemsetAsync(d_ws, 0, 800016, stream);   // flag + deg + cnt

    detect_kernel<<<16, 256, 0, stream>>>((const long long*)ei, flag);
    deg_count_kernel<<<NE / 256, 256, 0, stream>>>(ei, flag, ew, deg, cnt);
    scan_block<<<NBLK, 256, 0, stream>>>(cnt, rowstart, bsum);
    scan_bsums<<<1, 512, 0, stream>>>(bsum);
    scan_add<<<NBLK + 1, 256, 0, stream>>>(rowstart, bsum, cnt);
    fill_csr<<<NE / 256, 256, 0, stream>>>(ei, flag, ew, deg, rowstart, cnt, ecol, enorm);
    gather_prop<0><<<NN / 4, 256, 0, stream>>>(rowstart, ecol, enorm, x, nullptr, T1);
    gather_prop<1><<<NN / 4, 256, 0, stream>>>(rowstart, ecol, enorm, T1, x, T2);
    wprep_kernel<<<(FPAD * 768) / 256, 256, 0, stream>>>(W1, W2, W3, Wt);
    gemm_kernel<<<dim3((NN + 63) / 64, 3), 256, 0, stream>>>(x, T1, T2, Wt, b1, b2, b3, out);
}